// Round 3
// baseline (3074.071 us; speedup 1.0000x reference)
//
#include <hip/hip_runtime.h>
#include <hip/hip_bf16.h>

#define NN 20000
#define EE 160000

// ---------------------------------------------------------------------------
// Fully fused 3-layer MLP (+ optional LayerNorm, residual, atomic scatter).
//   C = MLP(A) ; A per mode:
//     mode 0: A0 row-major [M x K0]
//     mode 1: concat(nf[idx0], nf[idx1], ef) (K0=384), A0=A1=nf, A2=ef
//     mode 2: concat(A0, A1) both [M x 128]   (K0=256)
//   dec3: layers 0,1 normal; final layer is 128->3 (W2 is [128][3]), no LN.
// Block: 128 rows x 128 cols, 256 threads, 8x8 acc/thread.
// ---------------------------------------------------------------------------
#define SH_STRIDE 132   // 128 + 4 pad

__device__ __forceinline__ void stage_w(const float* __restrict__ W, int K, int k0,
                                        float* __restrict__ sW, int tid)
{
#pragma unroll
    for (int i = 0; i < 2; ++i) {
        int f = tid + i * 256;
        int k = f >> 5, c4 = f & 31;
        float4 v = make_float4(0.f, 0.f, 0.f, 0.f);
        if (k0 + k < K) v = *(const float4*)&W[(size_t)(k0 + k) * 128 + c4 * 4];
        *(float4*)&sW[k * 128 + c4 * 4] = v;
    }
}

__device__ __forceinline__ void mma_chunk(const float* aB, int aStride,
                                          const float* sW,
                                          int tm, int tn, float (&acc)[8][8])
{
#pragma unroll
    for (int kb = 0; kb < 16; kb += 4) {
        float4 a[8];
#pragma unroll
        for (int i = 0; i < 8; ++i)
            a[i] = *(const float4*)&aB[(tm + i * 16) * aStride + kb];
#pragma unroll
        for (int kk = 0; kk < 4; ++kk) {
            float4 w0 = *(const float4*)&sW[(kb + kk) * 128 + tn * 4];
            float4 w1 = *(const float4*)&sW[(kb + kk) * 128 + 64 + tn * 4];
#pragma unroll
            for (int i = 0; i < 8; ++i) {
                float av = (kk == 0) ? a[i].x : (kk == 1) ? a[i].y : (kk == 2) ? a[i].z : a[i].w;
                acc[i][0] += av * w0.x; acc[i][1] += av * w0.y;
                acc[i][2] += av * w0.z; acc[i][3] += av * w0.w;
                acc[i][4] += av * w1.x; acc[i][5] += av * w1.y;
                acc[i][6] += av * w1.z; acc[i][7] += av * w1.w;
            }
        }
    }
}

__global__ __launch_bounds__(256) void fused_mlp(
    const float* __restrict__ A0, const float* __restrict__ A1, const float* __restrict__ A2,
    const int* __restrict__ idx0, const int* __restrict__ idx1,
    const float* __restrict__ W0, const float* __restrict__ b0,
    const float* __restrict__ W1, const float* __restrict__ b1,
    const float* __restrict__ W2, const float* __restrict__ b2,
    const float* __restrict__ g, const float* __restrict__ be,
    float* __restrict__ out, float* __restrict__ residual, float* __restrict__ agg,
    int M, int K0, int mode, int dec3)
{
    // smem: sH (128 x SH_STRIDE) unioned with sA (128 x 16); sW (16 x 128) after.
    __shared__ float smem[128 * SH_STRIDE + 16 * 128];
    __shared__ int sIdx0[128], sIdx1[128];
    float* const sH = smem;
    float* const sA = smem;                  // union: sA only live during layer-0 K-loop
    float* const sW = smem + 128 * SH_STRIDE;

    const int tid = threadIdx.x;
    const int tn = tid & 15;
    const int tm = tid >> 4;
    const int m0 = blockIdx.x * 128;

    if (mode == 1 && tid < 128) {
        int row = m0 + tid;
        sIdx0[tid] = (row < M) ? idx0[row] : 0;
        sIdx1[tid] = (row < M) ? idx1[row] : 0;
    }
    __syncthreads();

    float acc[8][8];
#pragma unroll
    for (int i = 0; i < 8; ++i)
#pragma unroll
        for (int j = 0; j < 8; ++j) acc[i][j] = 0.f;

    // ---------------- layer 0: A (global/gather) @ W0 ----------------
    for (int k0 = 0; k0 < K0; k0 += 16) {
        stage_w(W0, K0, k0, sW, tid);
        if (mode == 0) {
#pragma unroll
            for (int i = 0; i < 8; ++i) {
                int f = tid + i * 256;
                int m = f >> 4, k = f & 15;
                int row = m0 + m;
                float v = 0.f;
                if (row < M && k0 + k < K0) v = A0[(size_t)row * K0 + k0 + k];
                sA[m * 16 + k] = v;
            }
        } else {
#pragma unroll
            for (int i = 0; i < 2; ++i) {
                int f = tid + i * 256;
                int m = f >> 2, kq = f & 3;
                int row = m0 + m;
                int gk = k0 + kq * 4;
                float4 v = make_float4(0.f, 0.f, 0.f, 0.f);
                if (row < M) {
                    int seg = gk >> 7, kc = gk & 127;
                    const float* src;
                    if (mode == 1) {
                        if (seg == 0)      src = A0 + (size_t)sIdx0[m] * 128;
                        else if (seg == 1) src = A1 + (size_t)sIdx1[m] * 128;
                        else               src = A2 + (size_t)row * 128;
                    } else {
                        src = (seg == 0) ? A0 + (size_t)row * 128 : A1 + (size_t)row * 128;
                    }
                    v = *(const float4*)&src[kc];
                }
                *(float4*)&sA[m * 16 + kq * 4] = v;
            }
        }
        __syncthreads();
        mma_chunk(sA, 16, sW, tm, tn, acc);
        __syncthreads();
    }

    // bias + relu, park h1 in sH
    {
        float4 bA = *(const float4*)&b0[tn * 4];
        float4 bB = *(const float4*)&b0[64 + tn * 4];
#pragma unroll
        for (int i = 0; i < 8; ++i) {
            int r = tm + i * 16;
            float4 hA, hB;
            hA.x = fmaxf(acc[i][0] + bA.x, 0.f); hA.y = fmaxf(acc[i][1] + bA.y, 0.f);
            hA.z = fmaxf(acc[i][2] + bA.z, 0.f); hA.w = fmaxf(acc[i][3] + bA.w, 0.f);
            hB.x = fmaxf(acc[i][4] + bB.x, 0.f); hB.y = fmaxf(acc[i][5] + bB.y, 0.f);
            hB.z = fmaxf(acc[i][6] + bB.z, 0.f); hB.w = fmaxf(acc[i][7] + bB.w, 0.f);
            *(float4*)&sH[r * SH_STRIDE + tn * 4] = hA;
            *(float4*)&sH[r * SH_STRIDE + 64 + tn * 4] = hB;
        }
    }
    __syncthreads();

    // ---------------- layer 1: h1 (LDS) @ W1 ----------------
#pragma unroll
    for (int i = 0; i < 8; ++i)
#pragma unroll
        for (int j = 0; j < 8; ++j) acc[i][j] = 0.f;
    for (int k0 = 0; k0 < 128; k0 += 16) {
        stage_w(W1, 128, k0, sW, tid);
        __syncthreads();
        mma_chunk(sH + k0, SH_STRIDE, sW, tm, tn, acc);
        __syncthreads();
    }
    {
        float4 bA = *(const float4*)&b1[tn * 4];
        float4 bB = *(const float4*)&b1[64 + tn * 4];
#pragma unroll
        for (int i = 0; i < 8; ++i) {
            int r = tm + i * 16;
            float4 hA, hB;
            hA.x = fmaxf(acc[i][0] + bA.x, 0.f); hA.y = fmaxf(acc[i][1] + bA.y, 0.f);
            hA.z = fmaxf(acc[i][2] + bA.z, 0.f); hA.w = fmaxf(acc[i][3] + bA.w, 0.f);
            hB.x = fmaxf(acc[i][4] + bB.x, 0.f); hB.y = fmaxf(acc[i][5] + bB.y, 0.f);
            hB.z = fmaxf(acc[i][6] + bB.z, 0.f); hB.w = fmaxf(acc[i][7] + bB.w, 0.f);
            *(float4*)&sH[r * SH_STRIDE + tn * 4] = hA;
            *(float4*)&sH[r * SH_STRIDE + 64 + tn * 4] = hB;
        }
    }
    __syncthreads();

    // ---------------- decoder tail: h2 @ W2[128x3] + b2 ----------------
    if (dec3) {
        for (int j = tid; j < 384; j += 256) sW[j] = W2[j];   // FIX: was `if (tid < 384)`,
        __syncthreads();                                       // left sW[256..383] stale
        for (int j = tid; j < 384; j += 256) {
            int r = j / 3, o = j - r * 3;
            int row = m0 + r;
            if (row < M) {
                float s = b2[o];
#pragma unroll 8
                for (int k = 0; k < 128; ++k) s += sH[r * SH_STRIDE + k] * sW[k * 3 + o];
                out[(size_t)row * 3 + o] = s;
            }
        }
        return;
    }

    // ---------------- layer 2: h2 (LDS) @ W2 ----------------
#pragma unroll
    for (int i = 0; i < 8; ++i)
#pragma unroll
        for (int j = 0; j < 8; ++j) acc[i][j] = 0.f;
    for (int k0 = 0; k0 < 128; k0 += 16) {
        stage_w(W2, 128, k0, sW, tid);
        __syncthreads();
        mma_chunk(sH + k0, SH_STRIDE, sW, tm, tn, acc);
        __syncthreads();
    }

    // ---------------- epilogue: bias, LayerNorm, residual, scatter ----------------
    {
        float4 bA = *(const float4*)&b2[tn * 4];
        float4 bB = *(const float4*)&b2[64 + tn * 4];
        float4 gA = *(const float4*)&g[tn * 4];
        float4 gB = *(const float4*)&g[64 + tn * 4];
        float4 eA = *(const float4*)&be[tn * 4];
        float4 eB = *(const float4*)&be[64 + tn * 4];
#pragma unroll
        for (int i = 0; i < 8; ++i) {
            float h[8];
            h[0] = acc[i][0] + bA.x; h[1] = acc[i][1] + bA.y;
            h[2] = acc[i][2] + bA.z; h[3] = acc[i][3] + bA.w;
            h[4] = acc[i][4] + bB.x; h[5] = acc[i][5] + bB.y;
            h[6] = acc[i][6] + bB.z; h[7] = acc[i][7] + bB.w;
            float s = h[0] + h[1] + h[2] + h[3] + h[4] + h[5] + h[6] + h[7];
            s += __shfl_xor(s, 1); s += __shfl_xor(s, 2);
            s += __shfl_xor(s, 4); s += __shfl_xor(s, 8);
            float mu = s * (1.f / 128.f);
            float q = 0.f;
#pragma unroll
            for (int j = 0; j < 8; ++j) { h[j] -= mu; q += h[j] * h[j]; }
            q += __shfl_xor(q, 1); q += __shfl_xor(q, 2);
            q += __shfl_xor(q, 4); q += __shfl_xor(q, 8);
            float rs = rsqrtf(q * (1.f / 128.f) + 1e-5f);
            float o[8];
            o[0] = h[0] * rs * gA.x + eA.x; o[1] = h[1] * rs * gA.y + eA.y;
            o[2] = h[2] * rs * gA.z + eA.z; o[3] = h[3] * rs * gA.w + eA.w;
            o[4] = h[4] * rs * gB.x + eB.x; o[5] = h[5] * rs * gB.y + eB.y;
            o[6] = h[6] * rs * gB.z + eB.z; o[7] = h[7] * rs * gB.w + eB.w;

            int rloc = tm + i * 16;
            int row = m0 + rloc;
            if (row < M) {
                int cA = tn * 4, cB = 64 + tn * 4;
                if (out) {
                    *(float4*)&out[(size_t)row * 128 + cA] = make_float4(o[0], o[1], o[2], o[3]);
                    *(float4*)&out[(size_t)row * 128 + cB] = make_float4(o[4], o[5], o[6], o[7]);
                }
                if (residual) {
                    float4 rA = *(const float4*)&residual[(size_t)row * 128 + cA];
                    float4 rB = *(const float4*)&residual[(size_t)row * 128 + cB];
                    rA.x += o[0]; rA.y += o[1]; rA.z += o[2]; rA.w += o[3];
                    rB.x += o[4]; rB.y += o[5]; rB.z += o[6]; rB.w += o[7];
                    *(float4*)&residual[(size_t)row * 128 + cA] = rA;
                    *(float4*)&residual[(size_t)row * 128 + cB] = rB;
                }
                if (agg) {
                    float* d = agg + (size_t)sIdx1[rloc] * 128;
                    atomicAdd(d + cA + 0, o[0]); atomicAdd(d + cA + 1, o[1]);
                    atomicAdd(d + cA + 2, o[2]); atomicAdd(d + cA + 3, o[3]);
                    atomicAdd(d + cB + 0, o[4]); atomicAdd(d + cB + 1, o[5]);
                    atomicAdd(d + cB + 2, o[6]); atomicAdd(d + cB + 3, o[7]);
                }
            }
        }
    }
}

__global__ void zero_kernel(float4* __restrict__ p, long n4)
{
    long i = (long)blockIdx.x * blockDim.x + threadIdx.x;
    if (i < n4) p[i] = make_float4(0.f, 0.f, 0.f, 0.f);
}

extern "C" void kernel_launch(void* const* d_in, const int* in_sizes, int n_in,
                              void* d_out, int out_size, void* d_ws, size_t ws_size,
                              hipStream_t stream)
{
    const float* node_x   = (const float*)d_in[0];
    const float* edge_x   = (const float*)d_in[1];
    const float* enc_n_W0 = (const float*)d_in[2];
    const float* enc_n_b0 = (const float*)d_in[3];
    const float* enc_n_W1 = (const float*)d_in[4];
    const float* enc_n_b1 = (const float*)d_in[5];
    const float* enc_n_W2 = (const float*)d_in[6];
    const float* enc_n_b2 = (const float*)d_in[7];
    const float* enc_n_g  = (const float*)d_in[8];
    const float* enc_n_be = (const float*)d_in[9];
    const float* enc_e_W0 = (const float*)d_in[10];
    const float* enc_e_b0 = (const float*)d_in[11];
    const float* enc_e_W1 = (const float*)d_in[12];
    const float* enc_e_b1 = (const float*)d_in[13];
    const float* enc_e_W2 = (const float*)d_in[14];
    const float* enc_e_b2 = (const float*)d_in[15];
    const float* enc_e_g  = (const float*)d_in[16];
    const float* enc_e_be = (const float*)d_in[17];
    const float* gnb_e_W0 = (const float*)d_in[18];
    const float* gnb_e_b0 = (const float*)d_in[19];
    const float* gnb_e_W1 = (const float*)d_in[20];
    const float* gnb_e_b1 = (const float*)d_in[21];
    const float* gnb_e_W2 = (const float*)d_in[22];
    const float* gnb_e_b2 = (const float*)d_in[23];
    const float* gnb_e_g  = (const float*)d_in[24];
    const float* gnb_e_be = (const float*)d_in[25];
    const float* gnb_n_W0 = (const float*)d_in[26];
    const float* gnb_n_b0 = (const float*)d_in[27];
    const float* gnb_n_W1 = (const float*)d_in[28];
    const float* gnb_n_b1 = (const float*)d_in[29];
    const float* gnb_n_W2 = (const float*)d_in[30];
    const float* gnb_n_b2 = (const float*)d_in[31];
    const float* gnb_n_g  = (const float*)d_in[32];
    const float* gnb_n_be = (const float*)d_in[33];
    const float* dec_W0   = (const float*)d_in[34];
    const float* dec_b0   = (const float*)d_in[35];
    const float* dec_W1   = (const float*)d_in[36];
    const float* dec_b1   = (const float*)d_in[37];
    const float* dec_W2   = (const float*)d_in[38];
    const float* dec_b2   = (const float*)d_in[39];
    const int*   senders  = (const int*)d_in[40];
    const int*   receivers= (const int*)d_in[41];
    float* out = (float*)d_out;

    const int N = NN, E = EE;

    // workspace: nf (N*128) + agg (N*128) + ef (E*128) = 102.4 MB
    float* nf  = (float*)d_ws;
    float* agg = nf  + (size_t)N * 128;
    float* ef  = agg + (size_t)N * 128;

    const dim3 gN((N + 127) / 128), gE((E + 127) / 128);

    // encoders
    fused_mlp<<<gN, 256, 0, stream>>>(node_x, nullptr, nullptr, nullptr, nullptr,
        enc_n_W0, enc_n_b0, enc_n_W1, enc_n_b1, enc_n_W2, enc_n_b2, enc_n_g, enc_n_be,
        nf, nullptr, nullptr, N, 12, 0, 0);
    fused_mlp<<<gE, 256, 0, stream>>>(edge_x, nullptr, nullptr, nullptr, nullptr,
        enc_e_W0, enc_e_b0, enc_e_W1, enc_e_b1, enc_e_W2, enc_e_b2, enc_e_g, enc_e_be,
        ef, nullptr, nullptr, E, 7, 0, 0);

    for (int s = 0; s < 3; ++s) {
        const float* eW0 = gnb_e_W0 + (size_t)s * 384 * 128;
        const float* eb0 = gnb_e_b0 + (size_t)s * 128;
        const float* eW1 = gnb_e_W1 + (size_t)s * 128 * 128;
        const float* eb1 = gnb_e_b1 + (size_t)s * 128;
        const float* eW2 = gnb_e_W2 + (size_t)s * 128 * 128;
        const float* eb2 = gnb_e_b2 + (size_t)s * 128;
        const float* eg  = gnb_e_g  + (size_t)s * 128;
        const float* ebe = gnb_e_be + (size_t)s * 128;
        const float* nW0 = gnb_n_W0 + (size_t)s * 256 * 128;
        const float* nb0 = gnb_n_b0 + (size_t)s * 128;
        const float* nW1 = gnb_n_W1 + (size_t)s * 128 * 128;
        const float* nb1 = gnb_n_b1 + (size_t)s * 128;
        const float* nW2 = gnb_n_W2 + (size_t)s * 128 * 128;
        const float* nb2 = gnb_n_b2 + (size_t)s * 128;
        const float* ng  = gnb_n_g  + (size_t)s * 128;
        const float* nbe = gnb_n_be + (size_t)s * 128;

        zero_kernel<<<dim3((N * 32 + 255) / 256), 256, 0, stream>>>((float4*)agg, (long)N * 32);
        // edge block: ef += LN(MLP(cat)); agg += scatter(LN(MLP(cat)))
        fused_mlp<<<gE, 256, 0, stream>>>(nf, nf, ef, senders, receivers,
            eW0, eb0, eW1, eb1, eW2, eb2, eg, ebe,
            nullptr, ef, agg, E, 384, 1, 0);
        // node block: nf += LN(MLP(concat(nf, agg)))
        fused_mlp<<<gN, 256, 0, stream>>>(nf, agg, nullptr, nullptr, nullptr,
            nW0, nb0, nW1, nb1, nW2, nb2, ng, nbe,
            nullptr, nf, nullptr, N, 256, 2, 0);
    }

    // decoder (fused 2 layers + 128->3 tail)
    fused_mlp<<<gN, 256, 0, stream>>>(nf, nullptr, nullptr, nullptr, nullptr,
        dec_W0, dec_b0, dec_W1, dec_b1, dec_W2, dec_b2, nullptr, nullptr,
        out, nullptr, nullptr, N, 128, 0, 1);
}

// Round 4
// 1156.183 us; speedup vs baseline: 2.6588x; 2.6588x over previous
//
#include <hip/hip_runtime.h>
#include <hip/hip_bf16.h>

#define NN 20000
#define EE 160000

typedef __attribute__((ext_vector_type(8))) short bf16x8;
typedef __attribute__((ext_vector_type(4))) float f32x4;

__device__ __forceinline__ unsigned short f2bf(float f) {
    unsigned int u = __float_as_uint(f);
    u += 0x7FFFu + ((u >> 16) & 1);   // RNE
    return (unsigned short)(u >> 16);
}
__device__ __forceinline__ float bf2f(short s) {
    return __uint_as_float(((unsigned int)(unsigned short)s) << 16);
}
__device__ __forceinline__ bf16x8 pack8(float4 a, float4 b) {
    bf16x8 r;
    r[0] = (short)f2bf(a.x); r[1] = (short)f2bf(a.y);
    r[2] = (short)f2bf(a.z); r[3] = (short)f2bf(a.w);
    r[4] = (short)f2bf(b.x); r[5] = (short)f2bf(b.y);
    r[6] = (short)f2bf(b.z); r[7] = (short)f2bf(b.w);
    return r;
}

#define SH_STRIDE 136   // bf16 elems/row: 272B = 17*16B -> 2-way banks on A-frag reads

// one MFMA sweep over all 8 col-tiles for 2 row-tiles at K-offset kb
__device__ __forceinline__ void mfma_sweep(f32x4 (&acc)[2][8], bf16x8 a0, bf16x8 a1,
                                           const short* __restrict__ Wt, int Kpad,
                                           int kb, int lm)
{
#pragma unroll
    for (int ct = 0; ct < 8; ++ct) {
        bf16x8 b = *(const bf16x8*)(Wt + (size_t)(ct * 16 + lm) * Kpad + kb);
        acc[0][ct] = __builtin_amdgcn_mfma_f32_16x16x32_bf16(a0, b, acc[0][ct], 0, 0, 0);
        acc[1][ct] = __builtin_amdgcn_mfma_f32_16x16x32_bf16(a1, b, acc[1][ct], 0, 0, 0);
    }
}

__device__ __forceinline__ void zero_acc(f32x4 (&acc)[2][8]) {
#pragma unroll
    for (int i = 0; i < 2; ++i)
#pragma unroll
        for (int j = 0; j < 8; ++j) acc[i][j] = (f32x4)(0.f);
}

// park acc -> sH as bf16 with bias+relu (wave-private rows)
__device__ __forceinline__ void park(const f32x4 (&acc)[2][8], const float* __restrict__ bias,
                                     short* __restrict__ sH, int w32, int lm, int lq)
{
#pragma unroll
    for (int ct = 0; ct < 8; ++ct) {
        float bb = bias[ct * 16 + lm];
#pragma unroll
        for (int rt = 0; rt < 2; ++rt) {
            int rbase = w32 + rt * 16 + lq * 4;
#pragma unroll
            for (int reg = 0; reg < 4; ++reg) {
                float v = fmaxf(acc[rt][ct][reg] + bb, 0.f);
                sH[(rbase + reg) * SH_STRIDE + ct * 16 + lm] = (short)f2bf(v);
            }
        }
    }
}

// modes: 0 = encoder (stage fp32 A0f K0<=32); 1 = edge gather (nfb,nfb,ef);
//        2 = node concat (nfb, agg fp32); 3 = decoder (nfb; tail 128->3)
__global__ __launch_bounds__(256) void gnn_mlp(
    const short* __restrict__ Wt0, int Kpad0,
    const short* __restrict__ Wt1, const short* __restrict__ Wt2,
    const float* __restrict__ b0, const float* __restrict__ b1, const float* __restrict__ b2,
    const float* __restrict__ g, const float* __restrict__ be,
    const float* __restrict__ A0f, int K0,          // mode0: src; mode3: dec_W2 [128x3]
    const short* __restrict__ nfb,
    const float* __restrict__ eff,                  // mode1: ef fp32 (seg2 + residual)
    const float* __restrict__ aggf,                 // mode2: agg fp32 (seg1)
    const int* __restrict__ senders, const int* __restrict__ receivers,
    float* __restrict__ outF, short* __restrict__ outB,
    float* __restrict__ aggOut, float* __restrict__ decOut,
    int M, int mode, int resid)
{
    __shared__ short sH[128 * SH_STRIDE];
    const int tid = threadIdx.x;
    const int lane = tid & 63;
    const int w = tid >> 6;           // wave 0..3
    const int lm = lane & 15;
    const int lq = lane >> 4;
    const int w32 = w * 32;
    const int m0 = blockIdx.x * 128;

    f32x4 acc[2][8];
    zero_acc(acc);

    // -------- layer 0 --------
    if (mode == 0) {
        // stage A (K0<=32, zero-padded) into own sH rows as bf16
#pragma unroll
        for (int i = 0; i < 16; ++i) {
            int flat = lane + i * 64;           // 0..1023
            int r = flat >> 5, k = flat & 31;
            int row = m0 + w32 + r;
            float v = (k < K0 && row < M) ? A0f[(size_t)row * K0 + k] : 0.f;
            sH[(w32 + r) * SH_STRIDE + k] = (short)f2bf(v);
        }
        bf16x8 a0 = *(const bf16x8*)&sH[(w32 + lm) * SH_STRIDE + lq * 8];
        bf16x8 a1 = *(const bf16x8*)&sH[(w32 + 16 + lm) * SH_STRIDE + lq * 8];
        mfma_sweep(acc, a0, a1, Wt0, Kpad0, lq * 8, lm);
    } else if (mode == 1) {
        int e0 = m0 + w32 + lm, e1 = m0 + w32 + 16 + lm;   // always < E (grid exact)
        int s0a = senders[e0], s0b = senders[e1];
        int s1a = receivers[e0], s1b = receivers[e1];
#pragma unroll
        for (int c = 0; c < 4; ++c) {   // seg 0: nf[senders]
            int kb = c * 32 + lq * 8;
            bf16x8 a0 = *(const bf16x8*)(nfb + (size_t)s0a * 128 + kb);
            bf16x8 a1 = *(const bf16x8*)(nfb + (size_t)s0b * 128 + kb);
            mfma_sweep(acc, a0, a1, Wt0, Kpad0, c * 32 + lq * 8, lm);
        }
#pragma unroll
        for (int c = 0; c < 4; ++c) {   // seg 1: nf[receivers]
            int kb = c * 32 + lq * 8;
            bf16x8 a0 = *(const bf16x8*)(nfb + (size_t)s1a * 128 + kb);
            bf16x8 a1 = *(const bf16x8*)(nfb + (size_t)s1b * 128 + kb);
            mfma_sweep(acc, a0, a1, Wt0, Kpad0, 128 + c * 32 + lq * 8, lm);
        }
#pragma unroll
        for (int c = 0; c < 4; ++c) {   // seg 2: ef (fp32 -> bf16)
            int kb = c * 32 + lq * 8;
            const float* p0 = eff + (size_t)e0 * 128 + kb;
            const float* p1 = eff + (size_t)e1 * 128 + kb;
            bf16x8 a0 = pack8(*(const float4*)p0, *(const float4*)(p0 + 4));
            bf16x8 a1 = pack8(*(const float4*)p1, *(const float4*)(p1 + 4));
            mfma_sweep(acc, a0, a1, Wt0, Kpad0, 256 + c * 32 + lq * 8, lm);
        }
    } else if (mode == 2) {
        int r0 = min(m0 + w32 + lm, M - 1), r1 = min(m0 + w32 + 16 + lm, M - 1);
#pragma unroll
        for (int c = 0; c < 4; ++c) {   // seg 0: nf
            int kb = c * 32 + lq * 8;
            bf16x8 a0 = *(const bf16x8*)(nfb + (size_t)r0 * 128 + kb);
            bf16x8 a1 = *(const bf16x8*)(nfb + (size_t)r1 * 128 + kb);
            mfma_sweep(acc, a0, a1, Wt0, Kpad0, c * 32 + lq * 8, lm);
        }
#pragma unroll
        for (int c = 0; c < 4; ++c) {   // seg 1: agg (fp32 -> bf16)
            int kb = c * 32 + lq * 8;
            const float* p0 = aggf + (size_t)r0 * 128 + kb;
            const float* p1 = aggf + (size_t)r1 * 128 + kb;
            bf16x8 a0 = pack8(*(const float4*)p0, *(const float4*)(p0 + 4));
            bf16x8 a1 = pack8(*(const float4*)p1, *(const float4*)(p1 + 4));
            mfma_sweep(acc, a0, a1, Wt0, Kpad0, 128 + c * 32 + lq * 8, lm);
        }
    } else {  // mode 3: decoder, A = nf_bf [M x 128]
        int r0 = min(m0 + w32 + lm, M - 1), r1 = min(m0 + w32 + 16 + lm, M - 1);
#pragma unroll
        for (int c = 0; c < 4; ++c) {
            int kb = c * 32 + lq * 8;
            bf16x8 a0 = *(const bf16x8*)(nfb + (size_t)r0 * 128 + kb);
            bf16x8 a1 = *(const bf16x8*)(nfb + (size_t)r1 * 128 + kb);
            mfma_sweep(acc, a0, a1, Wt0, Kpad0, c * 32 + lq * 8, lm);
        }
    }
    park(acc, b0, sH, w32, lm, lq);   // h1 (relu) -> LDS, wave-private

    // -------- layer 1 --------
    zero_acc(acc);
#pragma unroll
    for (int c = 0; c < 4; ++c) {
        int kb = c * 32 + lq * 8;
        bf16x8 a0 = *(const bf16x8*)&sH[(w32 + lm) * SH_STRIDE + kb];
        bf16x8 a1 = *(const bf16x8*)&sH[(w32 + 16 + lm) * SH_STRIDE + kb];
        mfma_sweep(acc, a0, a1, Wt1, 128, kb, lm);
    }
    park(acc, b1, sH, w32, lm, lq);   // h2 -> LDS

    // -------- decoder tail: h2 @ dec_W2[128x3] + b2 --------
    if (mode == 3) {
#pragma unroll
        for (int t = 0; t < 2; ++t) {
            int idx = t * 64 + lane;
            if (idx < 96) {
                int r = idx / 3, o = idx - r * 3;
                int row = m0 + w32 + r;
                if (row < M) {
                    float s = b2[o];
#pragma unroll
                    for (int kk = 0; kk < 16; ++kk) {
                        bf16x8 h8 = *(const bf16x8*)&sH[(w32 + r) * SH_STRIDE + kk * 8];
#pragma unroll
                        for (int j = 0; j < 8; ++j)
                            s += bf2f(h8[j]) * A0f[(kk * 8 + j) * 3 + o];
                    }
                    decOut[(size_t)row * 3 + o] = s;
                }
            }
        }
        return;
    }

    // -------- layer 2 --------
    zero_acc(acc);
#pragma unroll
    for (int c = 0; c < 4; ++c) {
        int kb = c * 32 + lq * 8;
        bf16x8 a0 = *(const bf16x8*)&sH[(w32 + lm) * SH_STRIDE + kb];
        bf16x8 a1 = *(const bf16x8*)&sH[(w32 + 16 + lm) * SH_STRIDE + kb];
        mfma_sweep(acc, a0, a1, Wt2, 128, kb, lm);
    }

    // -------- epilogue: bias + LN + residual + shadow + scatter --------
    float g_[8], be_[8], b2_[8];
#pragma unroll
    for (int ct = 0; ct < 8; ++ct) {
        g_[ct] = g[ct * 16 + lm]; be_[ct] = be[ct * 16 + lm]; b2_[ct] = b2[ct * 16 + lm];
    }
#pragma unroll
    for (int rt = 0; rt < 2; ++rt) {
#pragma unroll
        for (int reg = 0; reg < 4; ++reg) {
            int row = m0 + w32 + rt * 16 + lq * 4 + reg;
            float v[8];
            float s = 0.f;
#pragma unroll
            for (int ct = 0; ct < 8; ++ct) { v[ct] = acc[rt][ct][reg] + b2_[ct]; s += v[ct]; }
            s += __shfl_xor(s, 1); s += __shfl_xor(s, 2);
            s += __shfl_xor(s, 4); s += __shfl_xor(s, 8);
            float mu = s * (1.f / 128.f);
            float q = 0.f;
#pragma unroll
            for (int ct = 0; ct < 8; ++ct) { v[ct] -= mu; q += v[ct] * v[ct]; }
            q += __shfl_xor(q, 1); q += __shfl_xor(q, 2);
            q += __shfl_xor(q, 4); q += __shfl_xor(q, 8);
            float rs = rsqrtf(q * (1.f / 128.f) + 1e-5f);
            if (row < M) {
                int rcv = aggOut ? receivers[row] : 0;
#pragma unroll
                for (int ct = 0; ct < 8; ++ct) {
                    float o = v[ct] * rs * g_[ct] + be_[ct];
                    int col = ct * 16 + lm;
                    size_t gi = (size_t)row * 128 + col;
                    if (resid) {
                        float ns = outF[gi] + o;
                        outF[gi] = ns;
                        if (outB) outB[gi] = (short)f2bf(ns);
                    } else {
                        outF[gi] = o;
                        if (outB) outB[gi] = (short)f2bf(o);
                    }
                    if (aggOut) atomicAdd(aggOut + (size_t)rcv * 128 + col, o);
                }
            }
        }
    }
}

// ---------------------------------------------------------------------------
struct WtPrep { const float* src; int K; int Kpad; int dstOff; };
struct WtPrepAll { WtPrep m[26]; };

__global__ void wt_prep_kernel(WtPrepAll all, short* __restrict__ dst)
{
    const WtPrep p = all.m[blockIdx.y];
    int total = 128 * p.Kpad;
    int idx = blockIdx.x * 256 + threadIdx.x;
    if (idx >= total) return;
    int n = idx / p.Kpad, k = idx - n * p.Kpad;
    float v = (k < p.K) ? p.src[(size_t)k * 128 + n] : 0.f;
    dst[p.dstOff + idx] = (short)f2bf(v);
}

__global__ void zero_kernel(float4* __restrict__ p, long n4)
{
    long i = (long)blockIdx.x * blockDim.x + threadIdx.x;
    if (i < n4) p[i] = make_float4(0.f, 0.f, 0.f, 0.f);
}

// ---------------------------------------------------------------------------
extern "C" void kernel_launch(void* const* d_in, const int* in_sizes, int n_in,
                              void* d_out, int out_size, void* d_ws, size_t ws_size,
                              hipStream_t stream)
{
    const float* node_x   = (const float*)d_in[0];
    const float* edge_x   = (const float*)d_in[1];
    const float* enc_n_W0 = (const float*)d_in[2];
    const float* enc_n_b0 = (const float*)d_in[3];
    const float* enc_n_W1 = (const float*)d_in[4];
    const float* enc_n_b1 = (const float*)d_in[5];
    const float* enc_n_W2 = (const float*)d_in[6];
    const float* enc_n_b2 = (const float*)d_in[7];
    const float* enc_n_g  = (const float*)d_in[8];
    const float* enc_n_be = (const float*)d_in[9];
    const float* enc_e_W0 = (const float*)d_in[10];
    const float* enc_e_b0 = (const float*)d_in[11];
    const float* enc_e_W1 = (const float*)d_in[12];
    const float* enc_e_b1 = (const float*)d_in[13];
    const float* enc_e_W2 = (const float*)d_in[14];
    const float* enc_e_b2 = (const float*)d_in[15];
    const float* enc_e_g  = (const float*)d_in[16];
    const float* enc_e_be = (const float*)d_in[17];
    const float* gnb_e_W0 = (const float*)d_in[18];
    const float* gnb_e_b0 = (const float*)d_in[19];
    const float* gnb_e_W1 = (const float*)d_in[20];
    const float* gnb_e_b1 = (const float*)d_in[21];
    const float* gnb_e_W2 = (const float*)d_in[22];
    const float* gnb_e_b2 = (const float*)d_in[23];
    const float* gnb_e_g  = (const float*)d_in[24];
    const float* gnb_e_be = (const float*)d_in[25];
    const float* gnb_n_W0 = (const float*)d_in[26];
    const float* gnb_n_b0 = (const float*)d_in[27];
    const float* gnb_n_W1 = (const float*)d_in[28];
    const float* gnb_n_b1 = (const float*)d_in[29];
    const float* gnb_n_W2 = (const float*)d_in[30];
    const float* gnb_n_b2 = (const float*)d_in[31];
    const float* gnb_n_g  = (const float*)d_in[32];
    const float* gnb_n_be = (const float*)d_in[33];
    const float* dec_W0   = (const float*)d_in[34];
    const float* dec_b0   = (const float*)d_in[35];
    const float* dec_W1   = (const float*)d_in[36];
    const float* dec_b1   = (const float*)d_in[37];
    const float* dec_W2   = (const float*)d_in[38];
    const float* dec_b2   = (const float*)d_in[39];
    const int*   senders  = (const int*)d_in[40];
    const int*   receivers= (const int*)d_in[41];
    float* out = (float*)d_out;

    const int N = NN, E = EE;

    // workspace: nf, agg (fp32 N*128), ef (fp32 E*128), nf_bf (bf16), Wt pool (bf16)
    float* nf   = (float*)d_ws;
    float* agg  = nf + (size_t)N * 128;
    float* ef   = agg + (size_t)N * 128;
    short* nfbf = (short*)(ef + (size_t)E * 128);
    short* wt   = nfbf + (size_t)N * 128;

    // ---- build weight-prep table ----
    WtPrepAll tbl;
    int nMat = 0, off = 0;
    int o_encn[3], o_ence[3], o_ge0[3], o_ge1[3], o_ge2[3], o_gn0[3], o_gn1[3], o_gn2[3], o_dec[2];
    auto add = [&](const float* src, int K, int Kpad) {
        tbl.m[nMat].src = src; tbl.m[nMat].K = K; tbl.m[nMat].Kpad = Kpad;
        tbl.m[nMat].dstOff = off;
        int r = off; off += 128 * Kpad; ++nMat; return r;
    };
    o_encn[0] = add(enc_n_W0, 12, 32);
    o_encn[1] = add(enc_n_W1, 128, 128);
    o_encn[2] = add(enc_n_W2, 128, 128);
    o_ence[0] = add(enc_e_W0, 7, 32);
    o_ence[1] = add(enc_e_W1, 128, 128);
    o_ence[2] = add(enc_e_W2, 128, 128);
    for (int s = 0; s < 3; ++s) {
        o_ge0[s] = add(gnb_e_W0 + (size_t)s * 384 * 128, 384, 384);
        o_ge1[s] = add(gnb_e_W1 + (size_t)s * 128 * 128, 128, 128);
        o_ge2[s] = add(gnb_e_W2 + (size_t)s * 128 * 128, 128, 128);
        o_gn0[s] = add(gnb_n_W0 + (size_t)s * 256 * 128, 256, 256);
        o_gn1[s] = add(gnb_n_W1 + (size_t)s * 128 * 128, 128, 128);
        o_gn2[s] = add(gnb_n_W2 + (size_t)s * 128 * 128, 128, 128);
    }
    o_dec[0] = add(dec_W0, 128, 128);
    o_dec[1] = add(dec_W1, 128, 128);

    wt_prep_kernel<<<dim3(192, 26), 256, 0, stream>>>(tbl, wt);

    const dim3 gN((N + 127) / 128), gE(E / 128);

    // ---- encoders ----
    gnn_mlp<<<gN, 256, 0, stream>>>(wt + o_encn[0], 32, wt + o_encn[1], wt + o_encn[2],
        enc_n_b0, enc_n_b1, enc_n_b2, enc_n_g, enc_n_be,
        node_x, 12, nullptr, nullptr, nullptr, nullptr, nullptr,
        nf, nfbf, nullptr, nullptr, N, 0, 0);
    gnn_mlp<<<gE, 256, 0, stream>>>(wt + o_ence[0], 32, wt + o_ence[1], wt + o_ence[2],
        enc_e_b0, enc_e_b1, enc_e_b2, enc_e_g, enc_e_be,
        edge_x, 7, nullptr, nullptr, nullptr, nullptr, nullptr,
        ef, nullptr, nullptr, nullptr, E, 0, 0);

    // ---- 3 message-passing steps ----
    for (int s = 0; s < 3; ++s) {
        zero_kernel<<<dim3((N * 32 + 255) / 256), 256, 0, stream>>>((float4*)agg, (long)N * 32);
        gnn_mlp<<<gE, 256, 0, stream>>>(wt + o_ge0[s], 384, wt + o_ge1[s], wt + o_ge2[s],
            gnb_e_b0 + (size_t)s * 128, gnb_e_b1 + (size_t)s * 128, gnb_e_b2 + (size_t)s * 128,
            gnb_e_g + (size_t)s * 128, gnb_e_be + (size_t)s * 128,
            nullptr, 0, nfbf, ef, nullptr, senders, receivers,
            ef, nullptr, agg, nullptr, E, 1, 1);
        gnn_mlp<<<gN, 256, 0, stream>>>(wt + o_gn0[s], 256, wt + o_gn1[s], wt + o_gn2[s],
            gnb_n_b0 + (size_t)s * 128, gnb_n_b1 + (size_t)s * 128, gnb_n_b2 + (size_t)s * 128,
            gnb_n_g + (size_t)s * 128, gnb_n_be + (size_t)s * 128,
            nullptr, 0, nfbf, nullptr, agg, nullptr, nullptr,
            nf, nfbf, nullptr, nullptr, N, 2, 1);
    }

    // ---- decoder ----
    gnn_mlp<<<gN, 256, 0, stream>>>(wt + o_dec[0], 128, wt + o_dec[1], nullptr,
        dec_b0, dec_b1, dec_b2, nullptr, nullptr,
        dec_W2, 0, nfbf, nullptr, nullptr, nullptr, nullptr,
        nullptr, nullptr, nullptr, out, N, 3, 0);
}

// Round 6
// 963.483 us; speedup vs baseline: 3.1906x; 1.2000x over previous
//
#include <hip/hip_runtime.h>
#include <hip/hip_bf16.h>

#define NN 20000
#define EE 160000

typedef __attribute__((ext_vector_type(8))) short bf16x8;
typedef __attribute__((ext_vector_type(4))) float f32x4;

__device__ __forceinline__ unsigned short f2bf(float f) {
    unsigned int u = __float_as_uint(f);
    u += 0x7FFFu + ((u >> 16) & 1);   // RNE
    return (unsigned short)(u >> 16);
}
__device__ __forceinline__ float bf2f(short s) {
    return __uint_as_float(((unsigned int)(unsigned short)s) << 16);
}
__device__ __forceinline__ bf16x8 pack8(float4 a, float4 b) {
    bf16x8 r;
    r[0] = (short)f2bf(a.x); r[1] = (short)f2bf(a.y);
    r[2] = (short)f2bf(a.z); r[3] = (short)f2bf(a.w);
    r[4] = (short)f2bf(b.x); r[5] = (short)f2bf(b.y);
    r[6] = (short)f2bf(b.z); r[7] = (short)f2bf(b.w);
    return r;
}

#define SH_STRIDE 136   // bf16 elems/row

// one MFMA sweep over all 8 col-tiles for 2 row-tiles at K-offset kb
__device__ __forceinline__ void mfma_sweep(f32x4 (&acc)[2][8], bf16x8 a0, bf16x8 a1,
                                           const short* __restrict__ Wt, int Kpad,
                                           int kb, int lm)
{
#pragma unroll
    for (int ct = 0; ct < 8; ++ct) {
        bf16x8 b = *(const bf16x8*)(Wt + (size_t)(ct * 16 + lm) * Kpad + kb);
        acc[0][ct] = __builtin_amdgcn_mfma_f32_16x16x32_bf16(a0, b, acc[0][ct], 0, 0, 0);
        acc[1][ct] = __builtin_amdgcn_mfma_f32_16x16x32_bf16(a1, b, acc[1][ct], 0, 0, 0);
    }
}

__device__ __forceinline__ void zero_acc(f32x4 (&acc)[2][8]) {
#pragma unroll
    for (int i = 0; i < 2; ++i)
#pragma unroll
        for (int j = 0; j < 8; ++j) acc[i][j] = (f32x4)(0.f);
}

__device__ __forceinline__ void park(const f32x4 (&acc)[2][8], const float* __restrict__ bias,
                                     short* __restrict__ sH, int w32, int lm, int lq)
{
#pragma unroll
    for (int ct = 0; ct < 8; ++ct) {
        float bb = bias[ct * 16 + lm];
#pragma unroll
        for (int rt = 0; rt < 2; ++rt) {
            int rbase = w32 + rt * 16 + lq * 4;
#pragma unroll
            for (int reg = 0; reg < 4; ++reg) {
                float v = fmaxf(acc[rt][ct][reg] + bb, 0.f);
                sH[(rbase + reg) * SH_STRIDE + ct * 16 + lm] = (short)f2bf(v);
            }
        }
    }
}

// modes: 0 = encoder (stage fp32 A0f K0<=32); 1 = edge gather (nfb,nfb,ef) sorted by eList;
//        2 = node concat (nfb, agg fp32); 3 = decoder (nfb; tail 128->3)
__global__ __launch_bounds__(256) void gnn_mlp(
    const short* __restrict__ Wt0, int Kpad0,
    const short* __restrict__ Wt1, const short* __restrict__ Wt2,
    const float* __restrict__ b0, const float* __restrict__ b1, const float* __restrict__ b2,
    const float* __restrict__ g, const float* __restrict__ be,
    const float* __restrict__ A0f, int K0,          // mode0: src; mode3: dec_W2 [128x3]
    const short* __restrict__ nfb,
    const float* __restrict__ eff,                  // mode1: ef fp32 (seg2 + residual)
    const float* __restrict__ aggf,                 // mode2: agg fp32
    const int* __restrict__ eList,                  // mode1: sorted edge ids (or null = identity)
    const int* __restrict__ senders, const int* __restrict__ receivers,
    float* __restrict__ outF, short* __restrict__ outB,
    float* __restrict__ aggOut,                     // mode1: fp32 atomic dest
    float* __restrict__ decOut,
    int M, int mode, int resid)
{
    __shared__ short sH[128 * SH_STRIDE];
    __shared__ int sEdge[128], sRcv[128], sSnd[128];
    const int tid = threadIdx.x;
    const int lane = tid & 63;
    const int w = tid >> 6;           // wave 0..3
    const int lm = lane & 15;
    const int lq = lane >> 4;
    const int w32 = w * 32;
    const int m0 = blockIdx.x * 128;

    if (mode == 1) {
        if (tid < 128) {
            int slot = m0 + tid;                       // grid exact: slot < E
            int e = eList ? eList[slot] : slot;
            sEdge[tid] = e;
            sRcv[tid] = receivers[e];
            sSnd[tid] = senders[e];
        }
        __syncthreads();
    }

    f32x4 acc[2][8];
    zero_acc(acc);

    // -------- layer 0 --------
    if (mode == 0) {
#pragma unroll
        for (int i = 0; i < 8; ++i) {
            int flat = lane + i * 64;                  // per wave: 0..511 = 32 rows x 16? no:
            // 8*64 = 512 slots = 32 rows x 16 cols... need 32x32: do 2 elems per slot
            int r = flat >> 4, k2 = (flat & 15) * 2;
            int row = m0 + w32 + r;
            float v0 = (k2 < K0 && row < M) ? A0f[(size_t)row * K0 + k2] : 0.f;
            float v1 = (k2 + 1 < K0 && row < M) ? A0f[(size_t)row * K0 + k2 + 1] : 0.f;
            sH[(w32 + r) * SH_STRIDE + k2] = (short)f2bf(v0);
            sH[(w32 + r) * SH_STRIDE + k2 + 1] = (short)f2bf(v1);
        }
        bf16x8 a0 = *(const bf16x8*)&sH[(w32 + lm) * SH_STRIDE + lq * 8];
        bf16x8 a1 = *(const bf16x8*)&sH[(w32 + 16 + lm) * SH_STRIDE + lq * 8];
        mfma_sweep(acc, a0, a1, Wt0, Kpad0, lq * 8, lm);
    } else if (mode == 1) {
        int e0 = sEdge[w32 + lm], e1 = sEdge[w32 + 16 + lm];
        int s0a = sSnd[w32 + lm], s0b = sSnd[w32 + 16 + lm];
        int s1a = sRcv[w32 + lm], s1b = sRcv[w32 + 16 + lm];
#pragma unroll
        for (int c = 0; c < 4; ++c) {   // seg 0: nf[senders]
            int kb = c * 32 + lq * 8;
            bf16x8 a0 = *(const bf16x8*)(nfb + (size_t)s0a * 128 + kb);
            bf16x8 a1 = *(const bf16x8*)(nfb + (size_t)s0b * 128 + kb);
            mfma_sweep(acc, a0, a1, Wt0, Kpad0, c * 32 + lq * 8, lm);
        }
#pragma unroll
        for (int c = 0; c < 4; ++c) {   // seg 1: nf[receivers]
            int kb = c * 32 + lq * 8;
            bf16x8 a0 = *(const bf16x8*)(nfb + (size_t)s1a * 128 + kb);
            bf16x8 a1 = *(const bf16x8*)(nfb + (size_t)s1b * 128 + kb);
            mfma_sweep(acc, a0, a1, Wt0, Kpad0, 128 + c * 32 + lq * 8, lm);
        }
#pragma unroll
        for (int c = 0; c < 4; ++c) {   // seg 2: ef (fp32 -> bf16)
            int kb = c * 32 + lq * 8;
            const float* p0 = eff + (size_t)e0 * 128 + kb;
            const float* p1 = eff + (size_t)e1 * 128 + kb;
            bf16x8 a0 = pack8(*(const float4*)p0, *(const float4*)(p0 + 4));
            bf16x8 a1 = pack8(*(const float4*)p1, *(const float4*)(p1 + 4));
            mfma_sweep(acc, a0, a1, Wt0, Kpad0, 256 + c * 32 + lq * 8, lm);
        }
    } else if (mode == 2) {
        int r0 = min(m0 + w32 + lm, M - 1), r1 = min(m0 + w32 + 16 + lm, M - 1);
#pragma unroll
        for (int c = 0; c < 4; ++c) {   // seg 0: nf
            int kb = c * 32 + lq * 8;
            bf16x8 a0 = *(const bf16x8*)(nfb + (size_t)r0 * 128 + kb);
            bf16x8 a1 = *(const bf16x8*)(nfb + (size_t)r1 * 128 + kb);
            mfma_sweep(acc, a0, a1, Wt0, Kpad0, c * 32 + lq * 8, lm);
        }
#pragma unroll
        for (int c = 0; c < 4; ++c) {   // seg 1: agg (fp32 -> bf16)
            int kb = c * 32 + lq * 8;
            const float* p0 = aggf + (size_t)r0 * 128 + kb;
            const float* p1 = aggf + (size_t)r1 * 128 + kb;
            bf16x8 a0 = pack8(*(const float4*)p0, *(const float4*)(p0 + 4));
            bf16x8 a1 = pack8(*(const float4*)p1, *(const float4*)(p1 + 4));
            mfma_sweep(acc, a0, a1, Wt0, Kpad0, 128 + c * 32 + lq * 8, lm);
        }
    } else {  // mode 3: decoder
        int r0 = min(m0 + w32 + lm, M - 1), r1 = min(m0 + w32 + 16 + lm, M - 1);
#pragma unroll
        for (int c = 0; c < 4; ++c) {
            int kb = c * 32 + lq * 8;
            bf16x8 a0 = *(const bf16x8*)(nfb + (size_t)r0 * 128 + kb);
            bf16x8 a1 = *(const bf16x8*)(nfb + (size_t)r1 * 128 + kb);
            mfma_sweep(acc, a0, a1, Wt0, Kpad0, c * 32 + lq * 8, lm);
        }
    }
    park(acc, b0, sH, w32, lm, lq);   // h1 (relu) -> LDS, wave-private rows

    // -------- layer 1 --------
    zero_acc(acc);
#pragma unroll
    for (int c = 0; c < 4; ++c) {
        int kb = c * 32 + lq * 8;
        bf16x8 a0 = *(const bf16x8*)&sH[(w32 + lm) * SH_STRIDE + kb];
        bf16x8 a1 = *(const bf16x8*)&sH[(w32 + 16 + lm) * SH_STRIDE + kb];
        mfma_sweep(acc, a0, a1, Wt1, 128, kb, lm);
    }
    park(acc, b1, sH, w32, lm, lq);

    // -------- decoder tail: h2 @ dec_W2[128x3] + b2 --------
    if (mode == 3) {
#pragma unroll
        for (int t = 0; t < 2; ++t) {
            int idx = t * 64 + lane;
            if (idx < 96) {
                int r = idx / 3, o = idx - r * 3;
                int row = m0 + w32 + r;
                if (row < M) {
                    float s = b2[o];
#pragma unroll
                    for (int kk = 0; kk < 16; ++kk) {
                        bf16x8 h8 = *(const bf16x8*)&sH[(w32 + r) * SH_STRIDE + kk * 8];
#pragma unroll
                        for (int j = 0; j < 8; ++j)
                            s += bf2f(h8[j]) * A0f[(kk * 8 + j) * 3 + o];
                    }
                    decOut[(size_t)row * 3 + o] = s;
                }
            }
        }
        return;
    }

    // -------- layer 2 --------
    zero_acc(acc);
#pragma unroll
    for (int c = 0; c < 4; ++c) {
        int kb = c * 32 + lq * 8;
        bf16x8 a0 = *(const bf16x8*)&sH[(w32 + lm) * SH_STRIDE + kb];
        bf16x8 a1 = *(const bf16x8*)&sH[(w32 + 16 + lm) * SH_STRIDE + kb];
        mfma_sweep(acc, a0, a1, Wt2, 128, kb, lm);
    }

    // -------- epilogue: bias + LN (+ residual / shadow / merged scatter) --------
    float g_[8], be_[8], b2_[8];
#pragma unroll
    for (int ct = 0; ct < 8; ++ct) {
        g_[ct] = g[ct * 16 + lm]; be_[ct] = be[ct * 16 + lm]; b2_[ct] = b2[ct * 16 + lm];
    }

    if (mode == 1) {
        // rows = sorted edge slots; merge same-receiver runs in registers, one atomic per run
#pragma unroll
        for (int rt = 0; rt < 2; ++rt) {
            float run[8];
            int curRcv = -1;
#pragma unroll
            for (int reg = 0; reg < 4; ++reg) {
                int rloc = w32 + rt * 16 + lq * 4 + reg;   // consecutive sorted slots over reg
                float v[8];
                float s = 0.f;
#pragma unroll
                for (int ct = 0; ct < 8; ++ct) { v[ct] = acc[rt][ct][reg] + b2_[ct]; s += v[ct]; }
                s += __shfl_xor(s, 1); s += __shfl_xor(s, 2);
                s += __shfl_xor(s, 4); s += __shfl_xor(s, 8);
                float mu = s * (1.f / 128.f);
                float q = 0.f;
#pragma unroll
                for (int ct = 0; ct < 8; ++ct) { v[ct] -= mu; q += v[ct] * v[ct]; }
                q += __shfl_xor(q, 1); q += __shfl_xor(q, 2);
                q += __shfl_xor(q, 4); q += __shfl_xor(q, 8);
                float rs = rsqrtf(q * (1.f / 128.f) + 1e-5f);
                int e = sEdge[rloc];
                int rcv = sRcv[rloc];
                float o[8];
#pragma unroll
                for (int ct = 0; ct < 8; ++ct) {
                    o[ct] = v[ct] * rs * g_[ct] + be_[ct];
                    size_t gi = (size_t)e * 128 + ct * 16 + lm;
                    outF[gi] += o[ct];                      // ef residual
                }
                if (rcv != curRcv) {
                    if (curRcv >= 0) {
#pragma unroll
                        for (int ct = 0; ct < 8; ++ct)
                            atomicAdd(aggOut + (size_t)curRcv * 128 + ct * 16 + lm, run[ct]);
                    }
                    curRcv = rcv;
#pragma unroll
                    for (int ct = 0; ct < 8; ++ct) run[ct] = o[ct];
                } else {
#pragma unroll
                    for (int ct = 0; ct < 8; ++ct) run[ct] += o[ct];
                }
            }
            if (curRcv >= 0) {
#pragma unroll
                for (int ct = 0; ct < 8; ++ct)
                    atomicAdd(aggOut + (size_t)curRcv * 128 + ct * 16 + lm, run[ct]);
            }
        }
    } else {
#pragma unroll
        for (int rt = 0; rt < 2; ++rt) {
#pragma unroll
            for (int reg = 0; reg < 4; ++reg) {
                int row = m0 + w32 + rt * 16 + lq * 4 + reg;
                float v[8];
                float s = 0.f;
#pragma unroll
                for (int ct = 0; ct < 8; ++ct) { v[ct] = acc[rt][ct][reg] + b2_[ct]; s += v[ct]; }
                s += __shfl_xor(s, 1); s += __shfl_xor(s, 2);
                s += __shfl_xor(s, 4); s += __shfl_xor(s, 8);
                float mu = s * (1.f / 128.f);
                float q = 0.f;
#pragma unroll
                for (int ct = 0; ct < 8; ++ct) { v[ct] -= mu; q += v[ct] * v[ct]; }
                q += __shfl_xor(q, 1); q += __shfl_xor(q, 2);
                q += __shfl_xor(q, 4); q += __shfl_xor(q, 8);
                float rs = rsqrtf(q * (1.f / 128.f) + 1e-5f);
                if (row < M) {
#pragma unroll
                    for (int ct = 0; ct < 8; ++ct) {
                        float o = v[ct] * rs * g_[ct] + be_[ct];
                        size_t gi = (size_t)row * 128 + ct * 16 + lm;
                        if (resid) {
                            float ns = outF[gi] + o;
                            outF[gi] = ns;
                            if (outB) outB[gi] = (short)f2bf(ns);
                        } else {
                            outF[gi] = o;
                            if (outB) outB[gi] = (short)f2bf(o);
                        }
                    }
                }
            }
        }
    }
}

// ---------------------------------------------------------------------------
// counting-sort of edges by receiver: cnt -> exclusive-prefix cursor -> fill
// ---------------------------------------------------------------------------
__global__ void zero_i(int* __restrict__ p, int n)
{
    int i = blockIdx.x * 256 + threadIdx.x;
    if (i < n) p[i] = 0;
}
__global__ void csr_count(const int* __restrict__ recv, int* __restrict__ cnt, int E)
{
    int i = blockIdx.x * 256 + threadIdx.x;
    if (i < E) atomicAdd(&cnt[recv[i]], 1);
}
// single block, 256 threads, serial-chunk scan (trivially correct)
__global__ __launch_bounds__(256) void csr_scan(const int* __restrict__ cnt,
                                                int* __restrict__ cursor, int N)
{
    __shared__ int ssum[257];
    const int tid = threadIdx.x;
    const int per = (N + 255) / 256;
    const int lo = tid * per, hi = min(lo + per, N);
    int s = 0;
    for (int i = lo; i < hi; ++i) s += cnt[i];
    ssum[tid] = s;
    __syncthreads();
    if (tid == 0) {
        int run = 0;
        for (int i = 0; i < 256; ++i) { int t = ssum[i]; ssum[i] = run; run += t; }
        ssum[256] = run;
    }
    __syncthreads();
    int run = ssum[tid];
    for (int i = lo; i < hi; ++i) { int c = cnt[i]; cursor[i] = run; run += c; }
}
__global__ void csr_fill(const int* __restrict__ recv, int* __restrict__ cursor,
                         int* __restrict__ eList, int E)
{
    int i = blockIdx.x * 256 + threadIdx.x;
    if (i < E) {
        int pos = atomicAdd(&cursor[recv[i]], 1);
        eList[pos] = i;
    }
}

// ---------------------------------------------------------------------------
struct WtPrep { const float* src; int K; int Kpad; int dstOff; };
struct WtPrepAll { WtPrep m[26]; };

__global__ void wt_prep_kernel(WtPrepAll all, short* __restrict__ dst)
{
    const WtPrep p = all.m[blockIdx.y];
    int total = 128 * p.Kpad;
    int idx = blockIdx.x * 256 + threadIdx.x;
    if (idx >= total) return;
    int n = idx / p.Kpad, k = idx - n * p.Kpad;
    float v = (k < p.K) ? p.src[(size_t)k * 128 + n] : 0.f;
    dst[p.dstOff + idx] = (short)f2bf(v);
}

__global__ void zero_kernel(float4* __restrict__ p, long n4)
{
    long i = (long)blockIdx.x * blockDim.x + threadIdx.x;
    if (i < n4) p[i] = make_float4(0.f, 0.f, 0.f, 0.f);
}

// ---------------------------------------------------------------------------
extern "C" void kernel_launch(void* const* d_in, const int* in_sizes, int n_in,
                              void* d_out, int out_size, void* d_ws, size_t ws_size,
                              hipStream_t stream)
{
    const float* node_x   = (const float*)d_in[0];
    const float* edge_x   = (const float*)d_in[1];
    const float* enc_n_W0 = (const float*)d_in[2];
    const float* enc_n_b0 = (const float*)d_in[3];
    const float* enc_n_W1 = (const float*)d_in[4];
    const float* enc_n_b1 = (const float*)d_in[5];
    const float* enc_n_W2 = (const float*)d_in[6];
    const float* enc_n_b2 = (const float*)d_in[7];
    const float* enc_n_g  = (const float*)d_in[8];
    const float* enc_n_be = (const float*)d_in[9];
    const float* enc_e_W0 = (const float*)d_in[10];
    const float* enc_e_b0 = (const float*)d_in[11];
    const float* enc_e_W1 = (const float*)d_in[12];
    const float* enc_e_b1 = (const float*)d_in[13];
    const float* enc_e_W2 = (const float*)d_in[14];
    const float* enc_e_b2 = (const float*)d_in[15];
    const float* enc_e_g  = (const float*)d_in[16];
    const float* enc_e_be = (const float*)d_in[17];
    const float* gnb_e_W0 = (const float*)d_in[18];
    const float* gnb_e_b0 = (const float*)d_in[19];
    const float* gnb_e_W1 = (const float*)d_in[20];
    const float* gnb_e_b1 = (const float*)d_in[21];
    const float* gnb_e_W2 = (const float*)d_in[22];
    const float* gnb_e_b2 = (const float*)d_in[23];
    const float* gnb_e_g  = (const float*)d_in[24];
    const float* gnb_e_be = (const float*)d_in[25];
    const float* gnb_n_W0 = (const float*)d_in[26];
    const float* gnb_n_b0 = (const float*)d_in[27];
    const float* gnb_n_W1 = (const float*)d_in[28];
    const float* gnb_n_b1 = (const float*)d_in[29];
    const float* gnb_n_W2 = (const float*)d_in[30];
    const float* gnb_n_b2 = (const float*)d_in[31];
    const float* gnb_n_g  = (const float*)d_in[32];
    const float* gnb_n_be = (const float*)d_in[33];
    const float* dec_W0   = (const float*)d_in[34];
    const float* dec_b0   = (const float*)d_in[35];
    const float* dec_W1   = (const float*)d_in[36];
    const float* dec_b1   = (const float*)d_in[37];
    const float* dec_W2   = (const float*)d_in[38];
    const float* dec_b2   = (const float*)d_in[39];
    const int*   senders  = (const int*)d_in[40];
    const int*   receivers= (const int*)d_in[41];
    float* out = (float*)d_out;

    const int N = NN, E = EE;
    const int WT_TOTAL = (32 + 128 + 128 + 32 + 128 + 128 + 3 * (384 + 128 + 128 + 256 + 128 + 128)
                          + 128 + 128) * 128;   // shorts = 548864

    // ---- workspace layout: EXACT round-4 base + eList appended ----
    float* nf   = (float*)d_ws;                      // N*128 f32
    float* agg  = nf + (size_t)N * 128;              // N*128 f32
    float* ef   = agg + (size_t)N * 128;             // E*128 f32
    short* nfbf = (short*)(ef + (size_t)E * 128);    // N*128 bf16
    short* wt   = nfbf + (size_t)N * 128;            // WT_TOTAL bf16
    int*   eList = (int*)(wt + WT_TOTAL);            // E ints (sorted path only)
    size_t need_sorted = (size_t)((char*)(eList + E) - (char*)d_ws);
    // transient count/cursor overlay the agg region (dead until first step's zero)
    int* cnt    = (int*)agg;                          // N ints
    int* cursor = cnt + N;                            // N ints

    const bool useSorted = (ws_size >= need_sorted);  // ws_size constant -> graph-safe
    const int* eL = useSorted ? eList : nullptr;

    // ---- weight prep table ----
    WtPrepAll tbl;
    int nMat = 0, off = 0;
    int o_encn[3], o_ence[3], o_ge0[3], o_ge1[3], o_ge2[3], o_gn0[3], o_gn1[3], o_gn2[3], o_dec[2];
    auto add = [&](const float* src, int K, int Kpad) {
        tbl.m[nMat].src = src; tbl.m[nMat].K = K; tbl.m[nMat].Kpad = Kpad;
        tbl.m[nMat].dstOff = off;
        int r = off; off += 128 * Kpad; ++nMat; return r;
    };
    o_encn[0] = add(enc_n_W0, 12, 32);
    o_encn[1] = add(enc_n_W1, 128, 128);
    o_encn[2] = add(enc_n_W2, 128, 128);
    o_ence[0] = add(enc_e_W0, 7, 32);
    o_ence[1] = add(enc_e_W1, 128, 128);
    o_ence[2] = add(enc_e_W2, 128, 128);
    for (int s = 0; s < 3; ++s) {
        o_ge0[s] = add(gnb_e_W0 + (size_t)s * 384 * 128, 384, 384);
        o_ge1[s] = add(gnb_e_W1 + (size_t)s * 128 * 128, 128, 128);
        o_ge2[s] = add(gnb_e_W2 + (size_t)s * 128 * 128, 128, 128);
        o_gn0[s] = add(gnb_n_W0 + (size_t)s * 256 * 128, 256, 256);
        o_gn1[s] = add(gnb_n_W1 + (size_t)s * 128 * 128, 128, 128);
        o_gn2[s] = add(gnb_n_W2 + (size_t)s * 128 * 128, 128, 128);
    }
    o_dec[0] = add(dec_W0, 128, 128);
    o_dec[1] = add(dec_W1, 128, 128);

    wt_prep_kernel<<<dim3(192, 26), 256, 0, stream>>>(tbl, wt);

    // ---- build sorted edge list (before any use of agg region) ----
    if (useSorted) {
        zero_i<<<dim3((N + 255) / 256), 256, 0, stream>>>(cnt, N);
        csr_count<<<dim3((E + 255) / 256), 256, 0, stream>>>(receivers, cnt, E);
        csr_scan<<<dim3(1), 256, 0, stream>>>(cnt, cursor, N);
        csr_fill<<<dim3((E + 255) / 256), 256, 0, stream>>>(receivers, cursor, eList, E);
    }

    const dim3 gN((N + 127) / 128), gE(E / 128);

    // ---- encoders ----
    gnn_mlp<<<gN, 256, 0, stream>>>(wt + o_encn[0], 32, wt + o_encn[1], wt + o_encn[2],
        enc_n_b0, enc_n_b1, enc_n_b2, enc_n_g, enc_n_be,
        node_x, 12, nullptr, nullptr, nullptr, nullptr, nullptr, nullptr,
        nf, nfbf, nullptr, nullptr, N, 0, 0);
    gnn_mlp<<<gE, 256, 0, stream>>>(wt + o_ence[0], 32, wt + o_ence[1], wt + o_ence[2],
        enc_e_b0, enc_e_b1, enc_e_b2, enc_e_g, enc_e_be,
        edge_x, 7, nullptr, nullptr, nullptr, nullptr, nullptr, nullptr,
        ef, nullptr, nullptr, nullptr, E, 0, 0);

    // ---- 3 message-passing steps ----
    for (int s = 0; s < 3; ++s) {
        const float* eb0 = gnb_e_b0 + (size_t)s * 128;
        const float* eb1 = gnb_e_b1 + (size_t)s * 128;
        const float* eb2 = gnb_e_b2 + (size_t)s * 128;
        const float* eg  = gnb_e_g  + (size_t)s * 128;
        const float* ebe = gnb_e_be + (size_t)s * 128;
        const float* nb0 = gnb_n_b0 + (size_t)s * 128;
        const float* nb1 = gnb_n_b1 + (size_t)s * 128;
        const float* nb2 = gnb_n_b2 + (size_t)s * 128;
        const float* ng  = gnb_n_g  + (size_t)s * 128;
        const float* nbe = gnb_n_be + (size_t)s * 128;

        zero_kernel<<<dim3((N * 32 + 255) / 256), 256, 0, stream>>>((float4*)agg, (long)N * 32);
        // edge block: ef += LN(MLP(cat)); agg += merged-run atomic scatter
        gnn_mlp<<<gE, 256, 0, stream>>>(wt + o_ge0[s], 384, wt + o_ge1[s], wt + o_ge2[s],
            eb0, eb1, eb2, eg, ebe,
            nullptr, 0, nfbf, ef, nullptr, eL, senders, receivers,
            ef, nullptr, agg, nullptr, E, 1, 1);
        // node block: nf += LN(MLP(concat(nf, agg)))
        gnn_mlp<<<gN, 256, 0, stream>>>(wt + o_gn0[s], 256, wt + o_gn1[s], wt + o_gn2[s],
            nb0, nb1, nb2, ng, nbe,
            nullptr, 0, nfbf, nullptr, agg, nullptr, nullptr, nullptr,
            nf, nfbf, nullptr, nullptr, N, 2, 1);
    }

    // ---- decoder ----
    gnn_mlp<<<gN, 256, 0, stream>>>(wt + o_dec[0], 128, wt + o_dec[1], nullptr,
        dec_b0, dec_b1, dec_b2, nullptr, nullptr,
        dec_W2, 0, nfbf, nullptr, nullptr, nullptr, nullptr, nullptr,
        nullptr, nullptr, nullptr, out, N, 3, 0);
}